// Round 1
// baseline (1669.401 us; speedup 1.0000x reference)
//
#include <hip/hip_runtime.h>
#include <hip/hip_bf16.h>

// RecurrentLayer: h <- 0.5h + 0.5(relu(h) W_hid^T + x W_in^T + noise)
// Latency-bound sequential scan. 128 WGs x 1 wave; W register-resident;
// cross-WG exchange of relu(h) in bf16 via device-coherent (sc0 sc1) buffer
// with per-step arrival counters.

#define SEQ   512
#define NB    128
#define NI    128
#define NH    512
#define WBG   8      // batch groups (16 rows each)
#define WGG   16     // g groups per batch group (32 cols each)
#define BT    16
#define GT    32

typedef __attribute__((ext_vector_type(8))) short  short8;
typedef __attribute__((ext_vector_type(4))) float  float4v;
typedef __attribute__((ext_vector_type(4))) int    int4v;
typedef __attribute__((ext_vector_type(2))) int    int2v;

static __device__ __forceinline__ unsigned short f2bf(float f) {
    __hip_bfloat16 h = __float2bfloat16(f);
    unsigned short u;
    __builtin_memcpy(&u, &h, 2);
    return u;
}

static __device__ __forceinline__ short8 pack8(float4v a, float4v b) {
    short8 r;
    r[0] = (short)f2bf(a[0]); r[1] = (short)f2bf(a[1]);
    r[2] = (short)f2bf(a[2]); r[3] = (short)f2bf(a[3]);
    r[4] = (short)f2bf(b[0]); r[5] = (short)f2bf(b[1]);
    r[6] = (short)f2bf(b[2]); r[7] = (short)f2bf(b[3]);
    return r;
}

// 16 exchange-buffer loads, device-coherent, byte offsets 0..960 (c*64)
#define LOADR(idx, off) \
    asm volatile("global_load_dwordx4 %0, %1, off offset:" #off " sc0 sc1" \
                 : "=v"(rv[idx]) : "v"(rbase));

__global__ __launch_bounds__(64, 1) void rnn_step_kernel(
    const float* __restrict__ xin,    // [SEQ][NB][NI]
    const float* __restrict__ w_in,   // [NH][NI]
    const float* __restrict__ w_hid,  // [NH][NH]  (row g, col h)
    const float* __restrict__ noise,  // [SEQ][NH]
    float*       __restrict__ out,    // [SEQ][NB][NH] then [NB][NH] tail
    unsigned int*              cnt,   // [SEQ][WBG]
    unsigned short*            xbuf)  // [2][NB][NH] bf16 relu(h)
{
    const int lane = threadIdx.x;     // 0..63
    const int r16  = lane & 15;       // M/N index within MFMA tile
    const int kg   = lane >> 4;       // 0..3 k-group
    const int ib   = blockIdx.x & 7;  // batch group: peers share bid%8 -> same XCD (heuristic)
    const int jg   = blockIdx.x >> 3; // g group
    const int b0   = ib * BT;
    const int g0   = jg * GT;

    // ---- register-resident W_hid fragments: A[m=g(16)][k=h(32)] per chunk,
    //      lane: row = lane&15, k = (lane>>4)*8 + 0..7 (8 contiguous h)
    short8 wf[2][16];
#pragma unroll
    for (int t = 0; t < 2; ++t)
#pragma unroll
        for (int c = 0; c < 16; ++c) {
            const float* p = w_hid + (size_t)(g0 + t * 16 + r16) * NH + c * 32 + kg * 8;
            wf[t][c] = pack8(*(const float4v*)p, *(const float4v*)(p + 4));
        }
    // ---- register-resident W_in fragments (K = 128 -> 4 chunks)
    short8 wfin[2][4];
#pragma unroll
    for (int t = 0; t < 2; ++t)
#pragma unroll
        for (int c = 0; c < 4; ++c) {
            const float* p = w_in + (size_t)(g0 + t * 16 + r16) * NI + c * 32 + kg * 8;
            wfin[t][c] = pack8(*(const float4v*)p, *(const float4v*)(p + 4));
        }

    // persistent hidden state (D layout: col=lane&15 -> b, row=kg*4+reg -> g)
    float4v h0 = {0.f, 0.f, 0.f, 0.f};
    float4v h1 = {0.f, 0.f, 0.f, 0.f};

    const float* inp  = xin + (size_t)(b0 + r16) * NI + kg * 8;         // + s*NB*NI
    const float* nzp  = noise + g0 + kg * 4;                            // + s*NH (+16 for t=1)
    float*       outp = out + (size_t)(b0 + r16) * NH + g0 + kg * 4;    // + s*NB*NH (+16 for t=1)

    const unsigned long long xbase  = (unsigned long long)(uintptr_t)xbuf;
    const unsigned long long xw_off = ((unsigned long long)(b0 + r16) * NH + g0 + kg * 4) * 2ull;
    const unsigned long long xr_off = ((unsigned long long)(b0 + r16) * NH + kg * 8) * 2ull;
    const unsigned long long bufstride = (unsigned long long)NB * NH * 2ull;

#pragma unroll 1
    for (int s = 0; s < SEQ; ++s) {
        // ---- x-projection (h-independent; overlaps the wait shadow)
        const float* ip = inp + (size_t)s * NB * NI;
        short8 bin[4];
#pragma unroll
        for (int c = 0; c < 4; ++c) {
            float4v a = *(const float4v*)(ip + c * 32);
            float4v b = *(const float4v*)(ip + c * 32 + 4);
            bin[c] = pack8(a, b);
        }
        const float* np_ = nzp + (size_t)s * NH;
        float4v nz0 = *(const float4v*)np_;
        float4v nz1 = *(const float4v*)(np_ + 16);

        float4v acc0 = {0.f, 0.f, 0.f, 0.f};
        float4v acc1 = {0.f, 0.f, 0.f, 0.f};
#pragma unroll
        for (int c = 0; c < 4; ++c) {
            acc0 = __builtin_amdgcn_mfma_f32_16x16x32_bf16(wfin[0][c], bin[c], acc0, 0, 0, 0);
            acc1 = __builtin_amdgcn_mfma_f32_16x16x32_bf16(wfin[1][c], bin[c], acc1, 0, 0, 0);
        }

        if (s > 0) {
            // ---- wait for all 16 peers of this batch group to publish r[s-1]
            const unsigned int* cp = cnt + (size_t)(s - 1) * WBG + ib;
            unsigned int v;
            unsigned int guard = 0;
            do {
                v = __hip_atomic_load(cp, __ATOMIC_RELAXED, __HIP_MEMORY_SCOPE_AGENT);
            } while (v < (unsigned)WGG && ++guard < (1u << 20));
            __builtin_amdgcn_sched_barrier(0);

            // ---- read relu(h[s-1]) bf16: B[k=h][n=b], lane: col=lane&15,
            //      k = (lane>>4)*8 + 0..7; chunk c at byte offset c*64
            unsigned long long rbase = xbase + (unsigned long long)((s - 1) & 1) * bufstride + xr_off;
            int4v rv[16];
            LOADR(0, 0)   LOADR(1, 64)   LOADR(2, 128)  LOADR(3, 192)
            LOADR(4, 256) LOADR(5, 320)  LOADR(6, 384)  LOADR(7, 448)
            LOADR(8, 512) LOADR(9, 576)  LOADR(10, 640) LOADR(11, 704)
            LOADR(12, 768) LOADR(13, 832) LOADR(14, 896) LOADR(15, 960)
            asm volatile("s_waitcnt vmcnt(0)"
                         : "+v"(rv[0]), "+v"(rv[1]), "+v"(rv[2]), "+v"(rv[3]),
                           "+v"(rv[4]), "+v"(rv[5]), "+v"(rv[6]), "+v"(rv[7]),
                           "+v"(rv[8]), "+v"(rv[9]), "+v"(rv[10]), "+v"(rv[11]),
                           "+v"(rv[12]), "+v"(rv[13]), "+v"(rv[14]), "+v"(rv[15])
                         :
                         : "memory");
            __builtin_amdgcn_sched_barrier(0);

#pragma unroll
            for (int c = 0; c < 16; ++c) {
                short8 rb = __builtin_bit_cast(short8, rv[c]);
                acc0 = __builtin_amdgcn_mfma_f32_16x16x32_bf16(wf[0][c], rb, acc0, 0, 0, 0);
                acc1 = __builtin_amdgcn_mfma_f32_16x16x32_bf16(wf[1][c], rb, acc1, 0, 0, 0);
            }
        }

        // ---- state update
        float4v hn0, hn1;
#pragma unroll
        for (int r = 0; r < 4; ++r) {
            hn0[r] = 0.5f * h0[r] + 0.5f * (acc0[r] + nz0[r]);
            hn1[r] = 0.5f * h1[r] + 0.5f * (acc1[r] + nz1[r]);
        }
        h0 = hn0; h1 = hn1;

        // ---- publish relu(h) bf16 (device-coherent) then signal
        unsigned int q0 = (unsigned)f2bf(fmaxf(hn0[0], 0.f)) | ((unsigned)f2bf(fmaxf(hn0[1], 0.f)) << 16);
        unsigned int q1 = (unsigned)f2bf(fmaxf(hn0[2], 0.f)) | ((unsigned)f2bf(fmaxf(hn0[3], 0.f)) << 16);
        unsigned int q2 = (unsigned)f2bf(fmaxf(hn1[0], 0.f)) | ((unsigned)f2bf(fmaxf(hn1[1], 0.f)) << 16);
        unsigned int q3 = (unsigned)f2bf(fmaxf(hn1[2], 0.f)) | ((unsigned)f2bf(fmaxf(hn1[3], 0.f)) << 16);
        int2v e0; e0[0] = (int)q0; e0[1] = (int)q1;
        int2v e1; e1[0] = (int)q2; e1[1] = (int)q3;
        unsigned long long wb = xbase + (unsigned long long)(s & 1) * bufstride + xw_off;
        asm volatile("global_store_dwordx2 %0, %1, off sc0 sc1" :: "v"(wb), "v"(e0) : "memory");
        asm volatile("global_store_dwordx2 %0, %1, off offset:32 sc0 sc1" :: "v"(wb), "v"(e1) : "memory");
        asm volatile("s_waitcnt vmcnt(0)" ::: "memory");
        if (lane == 0) {
            __hip_atomic_fetch_add(cnt + (size_t)s * WBG + ib, 1u,
                                   __ATOMIC_RELAXED, __HIP_MEMORY_SCOPE_AGENT);
        }

        // ---- output writes (not on the sync critical path)
        float* op = outp + (size_t)s * NB * NH;
        *(float4v*)op        = hn0;
        *(float4v*)(op + 16) = hn1;
        if (s == SEQ - 1) {
            float* tp = out + (size_t)SEQ * NB * NH + (size_t)(b0 + r16) * NH + g0 + kg * 4;
            *(float4v*)tp        = hn0;
            *(float4v*)(tp + 16) = hn1;
        }
    }
}

extern "C" void kernel_launch(void* const* d_in, const int* in_sizes, int n_in,
                              void* d_out, int out_size, void* d_ws, size_t ws_size,
                              hipStream_t stream) {
    (void)in_sizes; (void)n_in; (void)out_size; (void)ws_size;
    const float* xin   = (const float*)d_in[0];
    const float* w_in  = (const float*)d_in[1];
    const float* w_hid = (const float*)d_in[2];
    const float* noise = (const float*)d_in[3];
    float* out = (float*)d_out;

    unsigned int*   cnt  = (unsigned int*)d_ws;                       // 512*8*4 = 16 KB
    unsigned short* xbuf = (unsigned short*)((char*)d_ws + SEQ * WBG * sizeof(unsigned int)); // 256 KB

    hipMemsetAsync(d_ws, 0, SEQ * WBG * sizeof(unsigned int), stream);
    hipLaunchKernelGGL(rnn_step_kernel, dim3(WBG * WGG), dim3(64), 0, stream,
                       xin, w_in, w_hid, noise, out, cnt, xbuf);
}

// Round 2
// 1471.335 us; speedup vs baseline: 1.1346x; 1.1346x over previous
//
#include <hip/hip_runtime.h>
#include <hip/hip_bf16.h>

// RecurrentLayer: h <- 0.5h + 0.5(relu(h) W_hid^T + x W_in^T + noise)
// Latency-bound sequential scan. 128 WGs x 1 wave; W register-resident.
// Flagless sync: relu(h) >= 0, so the bf16 sign bit carries a period-2 step
// tag. Consumers load-retry their 16KB slice until all words show the
// expected tag (no atomics, no separate poll round trip). A vmcnt(0) BEFORE
// each publish (waits only on stores issued a full step earlier ~= free)
// guarantees step s-2 data is overwritten before step s is visible, which
// excludes same-tag s-4 / initial-poison false accepts.

#define SEQ   512
#define NB    128
#define NI    128
#define NH    512
#define WBG   8      // batch groups (16 rows each)
#define WGG   16     // g groups per batch group (32 cols each)
#define BT    16
#define GT    32

typedef __attribute__((ext_vector_type(8))) short  short8;
typedef __attribute__((ext_vector_type(4))) float  float4v;
typedef __attribute__((ext_vector_type(4))) int    int4v;
typedef __attribute__((ext_vector_type(2))) int    int2v;

static __device__ __forceinline__ unsigned short f2bf(float f) {
    __hip_bfloat16 h = __float2bfloat16(f);
    unsigned short u;
    __builtin_memcpy(&u, &h, 2);
    return u;
}

static __device__ __forceinline__ short8 pack8(float4v a, float4v b) {
    short8 r;
    r[0] = (short)f2bf(a[0]); r[1] = (short)f2bf(a[1]);
    r[2] = (short)f2bf(a[2]); r[3] = (short)f2bf(a[3]);
    r[4] = (short)f2bf(b[0]); r[5] = (short)f2bf(b[1]);
    r[6] = (short)f2bf(b[2]); r[7] = (short)f2bf(b[3]);
    return r;
}

// device-coherent exchange loads, byte offsets 0..960 (c*64)
#define LOADR(idx, off) \
    asm volatile("global_load_dwordx4 %0, %1, off offset:" #off " sc0 sc1" \
                 : "=v"(rv[idx]) : "v"(rbase));

__global__ __launch_bounds__(64, 1) void rnn_step_kernel(
    const float* __restrict__ xin,    // [SEQ][NB][NI]
    const float* __restrict__ w_in,   // [NH][NI]
    const float* __restrict__ w_hid,  // [NH][NH]  (row g, col h)
    const float* __restrict__ noise,  // [SEQ][NH]
    float*       __restrict__ out,    // [SEQ][NB][NH] then [NB][NH] tail
    unsigned short*            xbuf)  // [2][NB][NH] bf16 relu(h), sign=tag
{
    const int lane = threadIdx.x;     // 0..63
    const int r16  = lane & 15;       // M/N index within MFMA tile
    const int kg   = lane >> 4;       // 0..3 k-group
    const int ib   = blockIdx.x & 7;  // batch group (peers share bid%8)
    const int jg   = blockIdx.x >> 3; // g group
    const int b0   = ib * BT;
    const int g0   = jg * GT;

    // ---- register-resident W_hid fragments: A[m=g(16)][k=h(32)] per chunk
    short8 wf[2][16];
#pragma unroll
    for (int t = 0; t < 2; ++t)
#pragma unroll
        for (int c = 0; c < 16; ++c) {
            const float* p = w_hid + (size_t)(g0 + t * 16 + r16) * NH + c * 32 + kg * 8;
            wf[t][c] = pack8(*(const float4v*)p, *(const float4v*)(p + 4));
        }
    // ---- register-resident W_in fragments (K = 128 -> 4 chunks)
    short8 wfin[2][4];
#pragma unroll
    for (int t = 0; t < 2; ++t)
#pragma unroll
        for (int c = 0; c < 4; ++c) {
            const float* p = w_in + (size_t)(g0 + t * 16 + r16) * NI + c * 32 + kg * 8;
            wfin[t][c] = pack8(*(const float4v*)p, *(const float4v*)(p + 4));
        }

    // persistent hidden state (D layout: col=lane&15 -> b, row=kg*4+reg -> g)
    float4v h0 = {0.f, 0.f, 0.f, 0.f};
    float4v h1 = {0.f, 0.f, 0.f, 0.f};

    const float* inp  = xin + (size_t)(b0 + r16) * NI + kg * 8;
    const float* nzp  = noise + g0 + kg * 4;
    float*       outp = out + (size_t)(b0 + r16) * NH + g0 + kg * 4;

    const unsigned long long xbase  = (unsigned long long)(uintptr_t)xbuf;
    const unsigned long long xw_off = ((unsigned long long)(b0 + r16) * NH + g0 + kg * 4) * 2ull;
    const unsigned long long xr_off = ((unsigned long long)(b0 + r16) * NH + kg * 8) * 2ull;
    const unsigned long long bufstride = (unsigned long long)NB * NH * 2ull;

#pragma unroll 1
    for (int s = 0; s < SEQ; ++s) {
        // ---- x-projection (h-independent; runs before the wait)
        const float* ip = inp + (size_t)s * NB * NI;
        short8 bin[4];
#pragma unroll
        for (int c = 0; c < 4; ++c) {
            float4v a = *(const float4v*)(ip + c * 32);
            float4v b = *(const float4v*)(ip + c * 32 + 4);
            bin[c] = pack8(a, b);
        }
        const float* np_ = nzp + (size_t)s * NH;
        float4v nz0 = *(const float4v*)np_;
        float4v nz1 = *(const float4v*)(np_ + 16);

        float4v acc0 = {0.f, 0.f, 0.f, 0.f};
        float4v acc1 = {0.f, 0.f, 0.f, 0.f};
#pragma unroll
        for (int c = 0; c < 4; ++c) {
            acc0 = __builtin_amdgcn_mfma_f32_16x16x32_bf16(wfin[0][c], bin[c], acc0, 0, 0, 0);
            acc1 = __builtin_amdgcn_mfma_f32_16x16x32_bf16(wfin[1][c], bin[c], acc1, 0, 0, 0);
        }

        if (s > 0) {
            const unsigned expTag = ((unsigned)(s - 1) >> 1) & 1u;  // tag of step s-1
            unsigned long long rbase = xbase + (unsigned long long)((s - 1) & 1) * bufstride + xr_off;
            int4v rv[16];
            unsigned guard = 0;
            for (;;) {
                LOADR(0, 0)    LOADR(1, 64)   LOADR(2, 128)  LOADR(3, 192)
                LOADR(4, 256)  LOADR(5, 320)  LOADR(6, 384)  LOADR(7, 448)
                LOADR(8, 512)  LOADR(9, 576)  LOADR(10, 640) LOADR(11, 704)
                LOADR(12, 768) LOADR(13, 832) LOADR(14, 896) LOADR(15, 960)
                asm volatile("s_waitcnt vmcnt(0)"
                             : "+v"(rv[0]), "+v"(rv[1]), "+v"(rv[2]), "+v"(rv[3]),
                               "+v"(rv[4]), "+v"(rv[5]), "+v"(rv[6]), "+v"(rv[7]),
                               "+v"(rv[8]), "+v"(rv[9]), "+v"(rv[10]), "+v"(rv[11]),
                               "+v"(rv[12]), "+v"(rv[13]), "+v"(rv[14]), "+v"(rv[15])
                             :
                             : "memory");
                // validate: every bf16 sign bit must equal expTag
                bool ok;
                if (expTag) {
                    unsigned a = 0xFFFFFFFFu;
#pragma unroll
                    for (int c = 0; c < 16; ++c)
                        a &= (unsigned)(rv[c][0] & rv[c][1] & rv[c][2] & rv[c][3]);
                    ok = (a & 0x80008000u) == 0x80008000u;
                } else {
                    unsigned o = 0u;
#pragma unroll
                    for (int c = 0; c < 16; ++c)
                        o |= (unsigned)(rv[c][0] | rv[c][1] | rv[c][2] | rv[c][3]);
                    ok = (o & 0x80008000u) == 0u;
                }
                if (__all(ok) || ++guard >= (1u << 16)) break;
            }
            __builtin_amdgcn_sched_barrier(0);

            // detag (clear sign bits) when tag==1
            if (expTag) {
#pragma unroll
                for (int c = 0; c < 16; ++c) {
                    rv[c][0] &= 0x7FFF7FFF; rv[c][1] &= 0x7FFF7FFF;
                    rv[c][2] &= 0x7FFF7FFF; rv[c][3] &= 0x7FFF7FFF;
                }
            }

            // 4 parallel MFMA chains of depth 8
            float4v p0a = {0.f,0.f,0.f,0.f}, p0b = {0.f,0.f,0.f,0.f};
            float4v p1a = {0.f,0.f,0.f,0.f}, p1b = {0.f,0.f,0.f,0.f};
#pragma unroll
            for (int c = 0; c < 8; ++c) {
                short8 rb0 = __builtin_bit_cast(short8, rv[c]);
                short8 rb1 = __builtin_bit_cast(short8, rv[c + 8]);
                p0a = __builtin_amdgcn_mfma_f32_16x16x32_bf16(wf[0][c],     rb0, p0a, 0, 0, 0);
                p0b = __builtin_amdgcn_mfma_f32_16x16x32_bf16(wf[0][c + 8], rb1, p0b, 0, 0, 0);
                p1a = __builtin_amdgcn_mfma_f32_16x16x32_bf16(wf[1][c],     rb0, p1a, 0, 0, 0);
                p1b = __builtin_amdgcn_mfma_f32_16x16x32_bf16(wf[1][c + 8], rb1, p1b, 0, 0, 0);
            }
#pragma unroll
            for (int r = 0; r < 4; ++r) {
                acc0[r] += p0a[r] + p0b[r];
                acc1[r] += p1a[r] + p1b[r];
            }
        }

        // ---- state update
        float4v hn0, hn1;
#pragma unroll
        for (int r = 0; r < 4; ++r) {
            hn0[r] = 0.5f * h0[r] + 0.5f * (acc0[r] + nz0[r]);
            hn1[r] = 0.5f * h1[r] + 0.5f * (acc1[r] + nz1[r]);
        }
        h0 = hn0; h1 = hn1;

        // ---- publish relu(h) bf16, sign bit = tag(s) = (s>>1)&1
        const unsigned tmask = ((s >> 1) & 1) ? 0x80008000u : 0u;
        unsigned q0 = ((unsigned)f2bf(fmaxf(hn0[0], 0.f)) | ((unsigned)f2bf(fmaxf(hn0[1], 0.f)) << 16)) | tmask;
        unsigned q1 = ((unsigned)f2bf(fmaxf(hn0[2], 0.f)) | ((unsigned)f2bf(fmaxf(hn0[3], 0.f)) << 16)) | tmask;
        unsigned q2 = ((unsigned)f2bf(fmaxf(hn1[0], 0.f)) | ((unsigned)f2bf(fmaxf(hn1[1], 0.f)) << 16)) | tmask;
        unsigned q3 = ((unsigned)f2bf(fmaxf(hn1[2], 0.f)) | ((unsigned)f2bf(fmaxf(hn1[3], 0.f)) << 16)) | tmask;
        int2v e0; e0[0] = (int)q0; e0[1] = (int)q1;
        int2v e1; e1[0] = (int)q2; e1[1] = (int)q3;
        unsigned long long wb = xbase + (unsigned long long)(s & 1) * bufstride + xw_off;
        // drain everything issued >= 1 step ago (incl. my s-2 publish) BEFORE
        // making step s visible — excludes same-tag s-4/poison false accepts.
        // Steady-state cost ~0: all counted ops are a full step old.
        asm volatile("s_waitcnt vmcnt(0)" ::: "memory");
        asm volatile("global_store_dwordx2 %0, %1, off sc0 sc1" :: "v"(wb), "v"(e0) : "memory");
        asm volatile("global_store_dwordx2 %0, %1, off offset:32 sc0 sc1" :: "v"(wb), "v"(e1) : "memory");

        // ---- output writes (fire and forget, off the sync path)
        float* op = outp + (size_t)s * NB * NH;
        *(float4v*)op        = hn0;
        *(float4v*)(op + 16) = hn1;
        if (s == SEQ - 1) {
            float* tp = out + (size_t)SEQ * NB * NH + (size_t)(b0 + r16) * NH + g0 + kg * 4;
            *(float4v*)tp        = hn0;
            *(float4v*)(tp + 16) = hn1;
        }
    }
}

extern "C" void kernel_launch(void* const* d_in, const int* in_sizes, int n_in,
                              void* d_out, int out_size, void* d_ws, size_t ws_size,
                              hipStream_t stream) {
    (void)in_sizes; (void)n_in; (void)out_size; (void)ws_size;
    const float* xin   = (const float*)d_in[0];
    const float* w_in  = (const float*)d_in[1];
    const float* w_hid = (const float*)d_in[2];
    const float* noise = (const float*)d_in[3];
    float* out = (float*)d_out;

    unsigned short* xbuf = (unsigned short*)d_ws;   // 2*128*512*2 = 256 KB

    // poison = sign bits set -> reads as "tag 1"; first reuse-exposed reads
    // expect tag 0, and the pre-publish vmcnt(0) ordering covers the rest.
    hipMemsetAsync(d_ws, 0xAA, 2 * NB * NH * sizeof(unsigned short), stream);
    hipLaunchKernelGGL(rnn_step_kernel, dim3(WBG * WGG), dim3(64), 0, stream,
                       xin, w_in, w_hid, noise, out, xbuf);
}